// Round 1
// baseline (37240.717 us; speedup 1.0000x reference)
//
#include <hip/hip_runtime.h>
#include <hip/hip_bf16.h>

// Problem constants (match reference)
#define B_   64
#define S_   128
#define T_   64
#define H_   1024
#define E_   512
#define V_   16000
#define ENC_ 2048   // 2*H... no: ENC = 2*H = 2048
#define XDIM_ (E_ + ENC_)   // 2560
#define G3_  (3 * H_)       // 3072

// ---------------------------------------------------------------------------
// Generic tiled fp32 GEMM:  C[M,N] = A[M,K] @ B[N,K]^T + bias[N]
// A row-major with row stride lda; B row-major (N rows of K) with row stride
// ldb (pointer may be pre-offset for column slices); C row stride ldc.
// Requires M%64==0, N%64==0, K%16==0 (true for every call here).
// ---------------------------------------------------------------------------
__global__ __launch_bounds__(256) void gemm_abt(
    const float* __restrict__ A, int lda,
    const float* __restrict__ Bm, int ldb,
    const float* __restrict__ bias,
    float* __restrict__ C, int ldc,
    int K)
{
    const int bm0 = blockIdx.y * 64;
    const int bn0 = blockIdx.x * 64;
    const int tid = threadIdx.x;

    __shared__ float As[16][64];   // As[k][m]
    __shared__ float Bs[16][64];   // Bs[k][n]

    const int lm  = tid >> 2;         // 0..63 (row within tile)
    const int lk4 = (tid & 3) << 2;   // 0,4,8,12 (k group)

    const int tx = tid & 15;          // n sub-tile
    const int ty = tid >> 4;          // m sub-tile

    float acc[4][4];
#pragma unroll
    for (int i = 0; i < 4; ++i)
#pragma unroll
        for (int j = 0; j < 4; ++j) acc[i][j] = 0.f;

    const float* Arow = A + (size_t)(bm0 + lm) * lda + lk4;
    const float* Brow = Bm + (size_t)(bn0 + lm) * ldb + lk4;

    for (int k0 = 0; k0 < K; k0 += 16) {
        float4 av = *reinterpret_cast<const float4*>(Arow + k0);
        float4 bv = *reinterpret_cast<const float4*>(Brow + k0);
        As[lk4 + 0][lm] = av.x;
        As[lk4 + 1][lm] = av.y;
        As[lk4 + 2][lm] = av.z;
        As[lk4 + 3][lm] = av.w;
        Bs[lk4 + 0][lm] = bv.x;
        Bs[lk4 + 1][lm] = bv.y;
        Bs[lk4 + 2][lm] = bv.z;
        Bs[lk4 + 3][lm] = bv.w;
        __syncthreads();

#pragma unroll
        for (int kk = 0; kk < 16; ++kk) {
            float4 a = *reinterpret_cast<const float4*>(&As[kk][ty << 2]);
            float4 b = *reinterpret_cast<const float4*>(&Bs[kk][tx << 2]);
            float ar[4] = {a.x, a.y, a.z, a.w};
            float br[4] = {b.x, b.y, b.z, b.w};
#pragma unroll
            for (int i = 0; i < 4; ++i)
#pragma unroll
                for (int j = 0; j < 4; ++j)
                    acc[i][j] = fmaf(ar[i], br[j], acc[i][j]);
        }
        __syncthreads();
    }

    float4 bias4 = make_float4(0.f, 0.f, 0.f, 0.f);
    if (bias) bias4 = *reinterpret_cast<const float4*>(bias + bn0 + (tx << 2));

#pragma unroll
    for (int i = 0; i < 4; ++i) {
        const int row = bm0 + (ty << 2) + i;
        float4 o;
        o.x = acc[i][0] + bias4.x;
        o.y = acc[i][1] + bias4.y;
        o.z = acc[i][2] + bias4.z;
        o.w = acc[i][3] + bias4.w;
        *reinterpret_cast<float4*>(C + (size_t)row * ldc + bn0 + (tx << 2)) = o;
    }
}

// ---------------------------------------------------------------------------
// Per-step attention: for block b
//   scores[s] = sum_h v[h] * tanh(q[b,h] + enc_proj[b,s,h])
//   alpha = softmax_s(scores)
//   ctx[b,e] = sum_s alpha[s] * enc[b,s,e]
// Also gathers x_emb = emb[token] into x[b, 0:E], writes ctx into x[b, E:].
// ---------------------------------------------------------------------------
__global__ __launch_bounds__(256) void attn_step(
    const float* __restrict__ encp,   // (B,S,H)
    const float* __restrict__ enc,    // (B,S,ENC)
    const float* __restrict__ vvec,   // (H)
    const float* __restrict__ q,      // (B,H)
    const int*   __restrict__ target, // (B,T)
    const float* __restrict__ emb,    // (V,E)
    float* __restrict__ x,            // (B, E+ENC)
    int t)
{
    const int b   = blockIdx.x;
    const int tid = threadIdx.x;

    __shared__ float q_s[H_];
    __shared__ float v_s[H_];
    __shared__ float sc_s[S_];

    for (int i = tid; i < H_; i += 256) {
        q_s[i] = q[b * H_ + i];
        v_s[i] = vvec[i];
    }
    // embedding gather
    const int tok = (t == 0) ? 1 : target[b * T_ + (t - 1)];
    for (int i = tid; i < E_; i += 256)
        x[b * XDIM_ + i] = emb[(size_t)tok * E_ + i];
    __syncthreads();

    const int wid  = tid >> 6;
    const int lane = tid & 63;

    for (int s = wid; s < S_; s += 4) {
        const float* ep = encp + ((size_t)b * S_ + s) * H_;
        float p = 0.f;
        for (int h = lane; h < H_; h += 64)
            p += v_s[h] * tanhf(q_s[h] + ep[h]);
#pragma unroll
        for (int off = 32; off; off >>= 1) p += __shfl_xor(p, off);
        if (lane == 0) sc_s[s] = p;
    }
    __syncthreads();

    // softmax over S=128, done by wave 0 (lane owns s=lane and s=lane+64)
    if (wid == 0) {
        float a0 = sc_s[lane];
        float a1 = sc_s[lane + 64];
        float m = fmaxf(a0, a1);
#pragma unroll
        for (int off = 32; off; off >>= 1) m = fmaxf(m, __shfl_xor(m, off));
        float e0 = expf(a0 - m);
        float e1 = expf(a1 - m);
        float ssum = e0 + e1;
#pragma unroll
        for (int off = 32; off; off >>= 1) ssum += __shfl_xor(ssum, off);
        float inv = 1.f / ssum;
        sc_s[lane]      = e0 * inv;
        sc_s[lane + 64] = e1 * inv;
    }
    __syncthreads();

    // ctx
    for (int e = tid; e < ENC_; e += 256) {
        const float* eb = enc + (size_t)b * S_ * ENC_ + e;
        float acc = 0.f;
#pragma unroll 4
        for (int s = 0; s < S_; ++s)
            acc = fmaf(sc_s[s], eb[(size_t)s * ENC_], acc);
        x[b * XDIM_ + E_ + e] = acc;
    }
}

// ---------------------------------------------------------------------------
// GRU pointwise combine: h_new = (1-z)*n + z*h_prev  -> h_all[(b*T+t)*H + j]
// ---------------------------------------------------------------------------
__device__ __forceinline__ float sigmoidf_(float x) {
    return 1.f / (1.f + expf(-x));
}

__global__ __launch_bounds__(256) void gru_step(
    const float* __restrict__ gi,     // (B, 3H)
    const float* __restrict__ gh,     // (B, 3H)
    const float* __restrict__ h_prev, // (B, H) with row stride ldh
    int ldh,
    float* __restrict__ h_out,        // h_all + t*H, row stride T*H
    int ldo)
{
    const int idx = blockIdx.x * 256 + threadIdx.x;  // 0 .. B*H-1
    const int b = idx >> 10;
    const int j = idx & (H_ - 1);

    const float ir  = gi[b * G3_ + j];
    const float iz  = gi[b * G3_ + H_ + j];
    const float inn = gi[b * G3_ + 2 * H_ + j];
    const float hr  = gh[b * G3_ + j];
    const float hz  = gh[b * G3_ + H_ + j];
    const float hn  = gh[b * G3_ + 2 * H_ + j];

    const float r = sigmoidf_(ir + hr);
    const float z = sigmoidf_(iz + hz);
    const float n = tanhf(inn + r * hn);
    const float hp = h_prev[(size_t)b * ldh + j];
    h_out[(size_t)b * ldo + j] = (1.f - z) * n + z * hp;
}

// ---------------------------------------------------------------------------
extern "C" void kernel_launch(void* const* d_in, const int* in_sizes, int n_in,
                              void* d_out, int out_size, void* d_ws, size_t ws_size,
                              hipStream_t stream) {
    const float* enc      = (const float*)d_in[0];   // (B,S,ENC)
    const float* enc_h    = (const float*)d_in[1];   // (1,B,H)
    const int*   target   = (const int*)  d_in[2];   // (B,T)
    const float* emb      = (const float*)d_in[3];   // (V,E)
    const float* Wa       = (const float*)d_in[4];   // (H, H+ENC)
    const float* ba       = (const float*)d_in[5];   // (H)
    const float* vvec     = (const float*)d_in[6];   // (H)
    const float* W_ih     = (const float*)d_in[7];   // (3H, E+ENC)
    const float* b_ih     = (const float*)d_in[8];   // (3H)
    const float* W_hh     = (const float*)d_in[9];   // (3H, H)
    const float* b_hh     = (const float*)d_in[10];  // (3H)
    const float* Wo       = (const float*)d_in[11];  // (V, H)
    const float* bo       = (const float*)d_in[12];  // (V)
    float* out = (float*)d_out;

    // Workspace layout (floats)
    float* ws = (float*)d_ws;
    float* encp  = ws;                           // B*S*H      = 8388608
    float* h_all = encp + (size_t)B_ * S_ * H_;  // B*T*H      = 4194304
    float* xbuf  = h_all + (size_t)B_ * T_ * H_; // B*XDIM     = 163840
    float* qbuf  = xbuf + (size_t)B_ * XDIM_;    // B*H        = 65536
    float* gibuf = qbuf + (size_t)B_ * H_;       // B*3H       = 196608
    float* ghbuf = gibuf + (size_t)B_ * G3_;     // B*3H       = 196608
    // total ~13.2M floats = ~53 MB

    const int LDW = H_ + ENC_;  // 3072, Wa row stride

    // 1) enc_proj = enc @ Wa_e^T + ba   (M=B*S, N=H, K=ENC)
    gemm_abt<<<dim3(H_ / 64, (B_ * S_) / 64), 256, 0, stream>>>(
        enc, ENC_, Wa + H_, LDW, ba, encp, H_, ENC_);

    // 2) recurrence
    for (int t = 0; t < T_; ++t) {
        const float* h_prev = (t == 0) ? enc_h : (h_all + (size_t)(t - 1) * H_);
        const int    ldh    = (t == 0) ? H_ : (T_ * H_);

        // q = h_prev @ Wa_q^T   (M=B, N=H, K=H)
        gemm_abt<<<dim3(H_ / 64, 1), 256, 0, stream>>>(
            h_prev, ldh, Wa, LDW, nullptr, qbuf, H_, H_);

        // attention + embedding gather -> xbuf
        attn_step<<<B_, 256, 0, stream>>>(encp, enc, vvec, qbuf, target, emb,
                                          xbuf, t);

        // gi = x @ W_ih^T + b_ih   (M=B, N=3H, K=E+ENC)
        gemm_abt<<<dim3(G3_ / 64, 1), 256, 0, stream>>>(
            xbuf, XDIM_, W_ih, XDIM_, b_ih, gibuf, G3_, XDIM_);

        // gh = h_prev @ W_hh^T + b_hh  (M=B, N=3H, K=H)
        gemm_abt<<<dim3(G3_ / 64, 1), 256, 0, stream>>>(
            h_prev, ldh, W_hh, H_, b_hh, ghbuf, G3_, H_);

        // GRU combine -> h_all[:, t, :]
        gru_step<<<(B_ * H_) / 256, 256, 0, stream>>>(
            gibuf, ghbuf, h_prev, ldh, h_all + (size_t)t * H_, T_ * H_);
    }

    // 3) out = h_all @ Wo^T + bo   (M=B*T, N=V, K=H), rows are (b,t) b-major
    gemm_abt<<<dim3(V_ / 64, (B_ * T_) / 64), 256, 0, stream>>>(
        h_all, H_, Wo, H_, bo, out, V_, H_);
}

// Round 2
// 5986.102 us; speedup vs baseline: 6.2212x; 6.2212x over previous
//
#include <hip/hip_runtime.h>
#include <hip/hip_bf16.h>

#define B_   64
#define S_   128
#define T_   64
#define H_   1024
#define E_   512
#define V_   16000
#define ENC_ 2048
#define XDIM_ (E_ + ENC_)   // 2560
#define G3_  (3 * H_)       // 3072
#define QGH_ (4 * H_)       // 4096 (q | gh)

typedef __attribute__((ext_vector_type(8))) short bf16x8;
typedef __attribute__((ext_vector_type(8))) unsigned short u16x8;
typedef __attribute__((ext_vector_type(4))) float f32x4;

__device__ __forceinline__ ushort f2bf(float x) {
    __hip_bfloat16 h = __float2bfloat16(x);
    return *reinterpret_cast<ushort*>(&h);
}
__device__ __forceinline__ float bf2f(ushort u) {
    return __uint_as_float((unsigned)u << 16);
}
__device__ __forceinline__ float sigmoidf_(float x) {
    return 1.f / (1.f + expf(-x));
}

// ---------------------------------------------------------------------------
// bf16 MFMA GEMM: C[M,N] = A[M,K] @ W[N,K]^T + bias[N]
// A,W bf16 row-major (lda/ldw multiples of 8). M%64==0, N%64==0, K%32==0.
// Out: fp32 (Cb==nullptr) or bf16 (Cb!=nullptr). Block 64x64, 4 waves,
// wave w owns cols [16w,16w+16). 16x16x32 MFMA; k-chunk loading is valid for
// any consistent A/B k-permutation (cancels in the dot product).
// ---------------------------------------------------------------------------
__global__ __launch_bounds__(256) void gemm_bf16(
    const ushort* __restrict__ A, int lda,
    const ushort* __restrict__ W, int ldw,
    const float* __restrict__ bias,
    float* __restrict__ Cf, ushort* __restrict__ Cb, int ldc,
    int K)
{
    const int bn0 = blockIdx.x * 64;
    const int bm0 = blockIdx.y * 64;
    const int tid = threadIdx.x;
    const int wid = tid >> 6;
    const int lane = tid & 63;

    __shared__ ushort As[64][40];   // +8 pad: 80B rows -> ~2-way b128 conflicts
    __shared__ ushort Ws[64][40];

    const int srow = tid >> 2;          // 0..63
    const int scol = (tid & 3) * 8;     // 0,8,16,24

    const ushort* Ag = A + (size_t)(bm0 + srow) * lda + scol;
    const ushort* Wg = W + (size_t)(bn0 + srow) * ldw + scol;

    f32x4 acc[4];
#pragma unroll
    for (int i = 0; i < 4; ++i) acc[i] = (f32x4){0.f, 0.f, 0.f, 0.f};

    const int frow = lane & 15;
    const int fk   = (lane >> 4) * 8;

    for (int k0 = 0; k0 < K; k0 += 32) {
        *reinterpret_cast<u16x8*>(&As[srow][scol]) =
            *reinterpret_cast<const u16x8*>(Ag + k0);
        *reinterpret_cast<u16x8*>(&Ws[srow][scol]) =
            *reinterpret_cast<const u16x8*>(Wg + k0);
        __syncthreads();

        bf16x8 bfrag = *reinterpret_cast<const bf16x8*>(&Ws[wid * 16 + frow][fk]);
#pragma unroll
        for (int rb = 0; rb < 4; ++rb) {
            bf16x8 afrag = *reinterpret_cast<const bf16x8*>(&As[rb * 16 + frow][fk]);
            acc[rb] = __builtin_amdgcn_mfma_f32_16x16x32_bf16(afrag, bfrag, acc[rb], 0, 0, 0);
        }
        __syncthreads();
    }

    const int cn = bn0 + wid * 16 + frow;
    const float bv = bias ? bias[cn] : 0.f;
    const int rgrp = (lane >> 4) * 4;
#pragma unroll
    for (int rb = 0; rb < 4; ++rb) {
#pragma unroll
        for (int r = 0; r < 4; ++r) {
            const int cm = bm0 + rb * 16 + rgrp + r;
            const float val = acc[rb][r] + bv;
            if (Cb) Cb[(size_t)cm * ldc + cn] = f2bf(val);
            else    Cf[(size_t)cm * ldc + cn] = val;
        }
    }
}

// ---------------------------------------------------------------------------
// Pack fp32 (strided, column slice) -> dense bf16
// ---------------------------------------------------------------------------
__global__ __launch_bounds__(256) void pack_bf16(
    const float* __restrict__ src, int src_ld, int c0, int ncols,
    ushort* __restrict__ dst, size_t total)
{
    size_t i = (size_t)blockIdx.x * 256 + threadIdx.x;
    const size_t stride = (size_t)gridDim.x * 256;
    for (; i < total; i += stride) {
        size_t r = i / (size_t)ncols;
        int c = (int)(i - r * (size_t)ncols);
        dst[i] = f2bf(src[r * (size_t)src_ld + c0 + c]);
    }
}

// Gather token embeddings: row (b*T+t) <- emb[token(b,t)], bf16
__global__ __launch_bounds__(256) void gather_emb(
    const int* __restrict__ target, const float* __restrict__ emb,
    ushort* __restrict__ dst)
{
    const int row = blockIdx.x;          // b*T + t
    const int b = row >> 6;              // T_ == 64
    const int t = row & 63;
    const int tok = (t == 0) ? 1 : target[b * T_ + t - 1];
    const float* e = emb + (size_t)tok * E_;
    ushort* d = dst + (size_t)row * E_;
    for (int c = threadIdx.x; c < E_; c += 256) d[c] = f2bf(e[c]);
}

// Pack bias [ba ; b_hh] -> (4096) fp32
__global__ __launch_bounds__(256) void pack_bhq(
    const float* __restrict__ ba, const float* __restrict__ bhh,
    float* __restrict__ dst)
{
    const int j = blockIdx.x * 256 + threadIdx.x;
    if (j < H_) dst[j] = ba[j];
    else if (j < QGH_) dst[j] = bhh[j - H_];
}

// ---------------------------------------------------------------------------
// Attention step: block per b (1024 threads).
// scores[s] = sum_h v[h]*tanh(q[b,h] + encp[b,s,h]); alpha=softmax; ctx=alpha@enc
// ---------------------------------------------------------------------------
__global__ __launch_bounds__(1024) void attn_step_k(
    const ushort* __restrict__ encp,   // (B,S,H) bf16
    const ushort* __restrict__ enc,    // (B,S,ENC) bf16
    const float* __restrict__ vvec,    // (H)
    const float* __restrict__ qgh,     // (B,4H): q = cols [0,H)
    ushort* __restrict__ ctx)          // (B,ENC) bf16
{
    const int b = blockIdx.x;
    const int tid = threadIdx.x;

    __shared__ float qs[H_];
    __shared__ float vs[H_];
    __shared__ float sc[S_];

    for (int i = tid; i < H_; i += 1024) {
        qs[i] = qgh[b * QGH_ + i];
        vs[i] = vvec[i];
    }
    __syncthreads();

    const int wid = tid >> 6;
    const int lane = tid & 63;
    const int h0 = lane * 16;

    for (int s = wid; s < S_; s += 16) {
        const ushort* ep = encp + ((size_t)b * S_ + s) * H_;
        float p = 0.f;
#pragma unroll
        for (int v8 = 0; v8 < 2; ++v8) {
            u16x8 ev = *reinterpret_cast<const u16x8*>(ep + h0 + v8 * 8);
#pragma unroll
            for (int j = 0; j < 8; ++j) {
                const int h = h0 + v8 * 8 + j;
                p += vs[h] * tanhf(qs[h] + bf2f(ev[j]));
            }
        }
#pragma unroll
        for (int off = 32; off; off >>= 1) p += __shfl_xor(p, off);
        if (lane == 0) sc[s] = p;
    }
    __syncthreads();

    if (tid < 64) {
        float a0 = sc[tid], a1 = sc[tid + 64];
        float m = fmaxf(a0, a1);
#pragma unroll
        for (int off = 32; off; off >>= 1) m = fmaxf(m, __shfl_xor(m, off));
        float e0 = expf(a0 - m), e1 = expf(a1 - m);
        float ssum = e0 + e1;
#pragma unroll
        for (int off = 32; off; off >>= 1) ssum += __shfl_xor(ssum, off);
        const float inv = 1.f / ssum;
        sc[tid] = e0 * inv;
        sc[tid + 64] = e1 * inv;
    }
    __syncthreads();

    // ctx: thread owns cols {2*tid, 2*tid+1}
    float c0 = 0.f, c1 = 0.f;
    const ushort* eb = enc + (size_t)b * S_ * ENC_ + 2 * tid;
#pragma unroll 4
    for (int s = 0; s < S_; ++s) {
        const unsigned u = *reinterpret_cast<const unsigned*>(eb + (size_t)s * ENC_);
        const float a = sc[s];
        c0 = fmaf(a, __uint_as_float(u << 16), c0);
        c1 = fmaf(a, __uint_as_float(u & 0xffff0000u), c1);
    }
    const unsigned packed = (unsigned)f2bf(c0) | ((unsigned)f2bf(c1) << 16);
    *reinterpret_cast<unsigned*>(ctx + (size_t)b * ENC_ + 2 * tid) = packed;
}

// ---------------------------------------------------------------------------
// GRU pointwise: h_new -> h_all_f (fp32) and h_all_b (bf16), row b*T+t
// ---------------------------------------------------------------------------
__global__ __launch_bounds__(256) void gru_step_k(
    const float* __restrict__ gictx,   // (B,3H)
    const float* __restrict__ giemb,   // (B*T,3H), row b*T+t (has b_ih)
    const float* __restrict__ qgh,     // (B,4H): gh = cols [H,4H) (has b_hh)
    const float* __restrict__ hprev, int ldh,
    float* __restrict__ hall_f,
    ushort* __restrict__ hall_b,
    int t)
{
    const int idx = blockIdx.x * 256 + threadIdx.x;   // 0..B*H-1
    const int b = idx >> 10;
    const int j = idx & (H_ - 1);

    const size_t gr = (size_t)(b * T_ + t) * G3_;
    const float ir = gictx[(size_t)b * G3_ + j]          + giemb[gr + j];
    const float iz = gictx[(size_t)b * G3_ + H_ + j]     + giemb[gr + H_ + j];
    const float in_ = gictx[(size_t)b * G3_ + 2 * H_ + j] + giemb[gr + 2 * H_ + j];

    const float* ghp = qgh + (size_t)b * QGH_ + H_;
    const float hr = ghp[j];
    const float hz = ghp[H_ + j];
    const float hn = ghp[2 * H_ + j];

    const float r = sigmoidf_(ir + hr);
    const float z = sigmoidf_(iz + hz);
    const float n = tanhf(in_ + r * hn);
    const float hp = hprev[(size_t)b * ldh + j];
    const float hnew = (1.f - z) * n + z * hp;

    const size_t ho = (size_t)b * (T_ * H_) + (size_t)t * H_ + j;
    hall_f[ho] = hnew;
    hall_b[ho] = f2bf(hnew);
}

// ---------------------------------------------------------------------------
static inline int pgrid(size_t total) {
    size_t nb = (total + 255) / 256;
    if (nb > 4096) nb = 4096;
    return (int)nb;
}

extern "C" void kernel_launch(void* const* d_in, const int* in_sizes, int n_in,
                              void* d_out, int out_size, void* d_ws, size_t ws_size,
                              hipStream_t stream) {
    const float* enc    = (const float*)d_in[0];   // (B,S,ENC)
    const float* enc_h  = (const float*)d_in[1];   // (1,B,H)
    const int*   target = (const int*)  d_in[2];   // (B,T)
    const float* emb    = (const float*)d_in[3];   // (V,E)
    const float* Wa     = (const float*)d_in[4];   // (H, H+ENC)
    const float* ba     = (const float*)d_in[5];   // (H)
    const float* vvec   = (const float*)d_in[6];   // (H)
    const float* W_ih   = (const float*)d_in[7];   // (3H, E+ENC)
    const float* b_ih   = (const float*)d_in[8];   // (3H)
    const float* W_hh   = (const float*)d_in[9];   // (3H, H)
    const float* b_hh   = (const float*)d_in[10];  // (3H)
    const float* Wo     = (const float*)d_in[11];  // (V, H)
    const float* bo     = (const float*)d_in[12];  // (V)
    float* out = (float*)d_out;

    // ---- workspace layout ----
    char* p = (char*)d_ws;
    auto alloc_u16 = [&](size_t n) { ushort* r = (ushort*)p; p += n * 2; return r; };
    auto alloc_f32 = [&](size_t n) { float* r = (float*)p; p += n * 4; return r; };

    ushort* enc_bf  = alloc_u16((size_t)B_ * S_ * ENC_);   // 16.78M
    ushort* encp_bf = alloc_u16((size_t)B_ * S_ * H_);     //  8.39M
    ushort* Wo_bf   = alloc_u16((size_t)V_ * H_);          // 16.38M
    ushort* Wae_bf  = alloc_u16((size_t)H_ * ENC_);        //  2.10M
    ushort* Whq_bf  = alloc_u16((size_t)QGH_ * H_);        //  4.19M
    ushort* Wie_bf  = alloc_u16((size_t)G3_ * ENC_);       //  6.29M
    ushort* Wiee_bf = alloc_u16((size_t)G3_ * E_);         //  1.57M
    ushort* ench_bf = alloc_u16((size_t)B_ * H_);          //  0.07M
    ushort* Xemb_bf = alloc_u16((size_t)B_ * T_ * E_);     //  2.10M
    ushort* hall_bf = alloc_u16((size_t)B_ * T_ * H_);     //  4.19M
    ushort* ctx_bf  = alloc_u16((size_t)B_ * ENC_);        //  0.13M
    float* hall_f   = alloc_f32((size_t)B_ * T_ * H_);     //  4.19M f32
    float* giemb    = alloc_f32((size_t)B_ * T_ * G3_);    // 12.58M f32
    float* qgh      = alloc_f32((size_t)B_ * QGH_);
    float* gictx    = alloc_f32((size_t)B_ * G3_);
    float* bhq      = alloc_f32((size_t)QGH_);
    // total ~193 MB

    const int LDW = H_ + ENC_;   // 3072

    // ---- pack / convert (parallel, once per call) ----
    pack_bf16<<<pgrid((size_t)B_*S_*ENC_), 256, 0, stream>>>(enc, ENC_, 0, ENC_, enc_bf, (size_t)B_*S_*ENC_);
    pack_bf16<<<pgrid((size_t)V_*H_), 256, 0, stream>>>(Wo, H_, 0, H_, Wo_bf, (size_t)V_*H_);
    pack_bf16<<<pgrid((size_t)H_*ENC_), 256, 0, stream>>>(Wa, LDW, H_, ENC_, Wae_bf, (size_t)H_*ENC_);
    pack_bf16<<<pgrid((size_t)H_*H_), 256, 0, stream>>>(Wa, LDW, 0, H_, Whq_bf, (size_t)H_*H_);
    pack_bf16<<<pgrid((size_t)G3_*H_), 256, 0, stream>>>(W_hh, H_, 0, H_, Whq_bf + (size_t)H_*H_, (size_t)G3_*H_);
    pack_bf16<<<pgrid((size_t)G3_*ENC_), 256, 0, stream>>>(W_ih, XDIM_, E_, ENC_, Wie_bf, (size_t)G3_*ENC_);
    pack_bf16<<<pgrid((size_t)G3_*E_), 256, 0, stream>>>(W_ih, XDIM_, 0, E_, Wiee_bf, (size_t)G3_*E_);
    pack_bf16<<<pgrid((size_t)B_*H_), 256, 0, stream>>>(enc_h, H_, 0, H_, ench_bf, (size_t)B_*H_);
    gather_emb<<<B_*T_, 256, 0, stream>>>(target, emb, Xemb_bf);
    pack_bhq<<<QGH_/256, 256, 0, stream>>>(ba, b_hh, bhq);

    // ---- big parallel GEMMs ----
    // enc_proj (bf16 out): (B*S,H) = enc_bf(B*S,ENC) @ Wae^T
    gemm_bf16<<<dim3(H_/64, (B_*S_)/64), 256, 0, stream>>>(
        enc_bf, ENC_, Wae_bf, ENC_, nullptr, nullptr, encp_bf, H_, ENC_);
    // gi_emb (fp32): (B*T,3H) = Xemb @ W_ih[:, :E]^T + b_ih
    gemm_bf16<<<dim3(G3_/64, (B_*T_)/64), 256, 0, stream>>>(
        Xemb_bf, E_, Wiee_bf, E_, b_ih, giemb, nullptr, G3_, E_);

    // ---- recurrence ----
    for (int t = 0; t < T_; ++t) {
        const ushort* hprev_bf = (t == 0) ? ench_bf : (hall_bf + (size_t)(t-1) * H_);
        const int lda_h = (t == 0) ? H_ : (T_ * H_);
        const float* hprev_f = (t == 0) ? enc_h : (hall_f + (size_t)(t-1) * H_);
        const int ldh = (t == 0) ? H_ : (T_ * H_);

        // qgh = h_prev @ [Wa_q; W_hh]^T + [ba; b_hh]   (M=64,N=4096,K=1024)
        gemm_bf16<<<dim3(QGH_/64, 1), 256, 0, stream>>>(
            hprev_bf, lda_h, Whq_bf, H_, bhq, qgh, nullptr, QGH_, H_);

        attn_step_k<<<B_, 1024, 0, stream>>>(encp_bf, enc_bf, vvec, qgh, ctx_bf);

        // gi_ctx = ctx @ W_ih[:, E:]^T   (M=64,N=3072,K=2048)
        gemm_bf16<<<dim3(G3_/64, 1), 256, 0, stream>>>(
            ctx_bf, ENC_, Wie_bf, ENC_, nullptr, gictx, nullptr, G3_, ENC_);

        gru_step_k<<<(B_*H_)/256, 256, 0, stream>>>(
            gictx, giemb, qgh, hprev_f, ldh, hall_f, hall_bf, t);
    }

    // ---- output projection: (B*T,V) = hall_bf @ Wo^T + bo ----
    gemm_bf16<<<dim3(V_/64, (B_*T_)/64), 256, 0, stream>>>(
        hall_bf, H_, Wo_bf, H_, bo, out, nullptr, V_, H_);
}

// Round 3
// 3884.982 us; speedup vs baseline: 9.5858x; 1.5408x over previous
//
#include <hip/hip_runtime.h>
#include <hip/hip_bf16.h>

#define B_   64
#define S_   128
#define T_   64
#define H_   1024
#define E_   512
#define V_   16000
#define ENC_ 2048
#define XDIM_ (E_ + ENC_)   // 2560
#define G3_  (3 * H_)       // 3072
#define QGH_ (4 * H_)       // 4096 (q | gh)

typedef __attribute__((ext_vector_type(8))) short bf16x8;
typedef __attribute__((ext_vector_type(8))) unsigned short u16x8;
typedef __attribute__((ext_vector_type(4))) float f32x4;

__device__ __forceinline__ ushort f2bf(float x) {
    __hip_bfloat16 h = __float2bfloat16(x);
    return *reinterpret_cast<ushort*>(&h);
}
__device__ __forceinline__ float bf2f(ushort u) {
    return __uint_as_float((unsigned)u << 16);
}
__device__ __forceinline__ float sigmoidf_(float x) {
    return 1.f / (1.f + expf(-x));
}

// async global->LDS, 16B per lane (wave-uniform LDS base + lane*16)
__device__ __forceinline__ void gload_lds16(const ushort* g, ushort* l) {
    __builtin_amdgcn_global_load_lds(
        (const __attribute__((address_space(1))) unsigned int*)g,
        (__attribute__((address_space(3))) unsigned int*)l, 16, 0, 0);
}

// ---------------------------------------------------------------------------
// m97-structure GEMM: C[M,N] = A[M,K] @ W[N,K]^T + bias[N]
// 128x128 tile, BK=32, 256 threads (4 waves, each owns a 64x64 quadrant).
// A,W bf16 row-major. M%128==0, N%128==0, K%32==0.
// ---------------------------------------------------------------------------
__global__ __launch_bounds__(256) void gemm128_bf16(
    const ushort* __restrict__ A, int lda,
    const ushort* __restrict__ W, int ldw,
    const float* __restrict__ bias,
    float* __restrict__ Cf, ushort* __restrict__ Cb, int ldc,
    int K)
{
    const int bn0 = blockIdx.x * 128;
    const int bm0 = blockIdx.y * 128;
    const int tid = threadIdx.x;
    const int wv  = tid >> 6;
    const int lane = tid & 63;

    __shared__ ushort As[128 * 32];   // row-major [128][32]
    __shared__ ushort Bs[128 * 32];

    const int srow = tid >> 2;            // 0..63
    const int scol = (tid & 3) * 8;       // bf16 col offset

    const ushort* gA0 = A + (size_t)(bm0 + srow) * lda + scol;
    const ushort* gA1 = gA0 + (size_t)64 * lda;
    const ushort* gB0 = W + (size_t)(bn0 + srow) * ldw + scol;
    const ushort* gB1 = gB0 + (size_t)64 * ldw;

    ushort* lA0 = &As[tid * 8];
    ushort* lA1 = &As[2048 + tid * 8];
    ushort* lB0 = &Bs[tid * 8];
    ushort* lB1 = &Bs[2048 + tid * 8];

    const int wr0 = (wv >> 1) * 64;
    const int wc0 = (wv & 1) * 64;
    const int frow = lane & 15;
    const int fk   = (lane >> 4) * 8;

    f32x4 acc[4][4];
#pragma unroll
    for (int i = 0; i < 4; ++i)
#pragma unroll
        for (int j = 0; j < 4; ++j) acc[i][j] = (f32x4){0.f, 0.f, 0.f, 0.f};

    for (int k0 = 0; k0 < K; k0 += 32) {
        gload_lds16(gA0 + k0, lA0);
        gload_lds16(gA1 + k0, lA1);
        gload_lds16(gB0 + k0, lB0);
        gload_lds16(gB1 + k0, lB1);
        __syncthreads();

        bf16x8 af[4], bf[4];
#pragma unroll
        for (int rb = 0; rb < 4; ++rb)
            af[rb] = *reinterpret_cast<const bf16x8*>(&As[(wr0 + rb * 16 + frow) * 32 + fk]);
#pragma unroll
        for (int cb = 0; cb < 4; ++cb)
            bf[cb] = *reinterpret_cast<const bf16x8*>(&Bs[(wc0 + cb * 16 + frow) * 32 + fk]);
#pragma unroll
        for (int rb = 0; rb < 4; ++rb)
#pragma unroll
            for (int cb = 0; cb < 4; ++cb)
                acc[rb][cb] = __builtin_amdgcn_mfma_f32_16x16x32_bf16(af[rb], bf[cb], acc[rb][cb], 0, 0, 0);
        __syncthreads();
    }

    const int quad = lane >> 4;
#pragma unroll
    for (int cb = 0; cb < 4; ++cb) {
        const int col = bn0 + wc0 + cb * 16 + frow;
        const float bv = bias ? bias[col] : 0.f;
#pragma unroll
        for (int rb = 0; rb < 4; ++rb) {
            const int row0 = bm0 + wr0 + rb * 16 + quad * 4;
            f32x4 a = acc[rb][cb];
#pragma unroll
            for (int r = 0; r < 4; ++r) {
                const float val = a[r] + bv;
                if (Cb) Cb[(size_t)(row0 + r) * ldc + col] = f2bf(val);
                else    Cf[(size_t)(row0 + r) * ldc + col] = val;
            }
        }
    }
}

// ---------------------------------------------------------------------------
// Packs
// ---------------------------------------------------------------------------
__global__ __launch_bounds__(256) void pack_bf16(
    const float* __restrict__ src, int src_ld, int c0, int ncols,
    ushort* __restrict__ dst, size_t total)
{
    size_t i = (size_t)blockIdx.x * 256 + threadIdx.x;
    const size_t stride = (size_t)gridDim.x * 256;
    for (; i < total; i += stride) {
        size_t r = i / (size_t)ncols;
        int c = (int)(i - r * (size_t)ncols);
        dst[i] = f2bf(src[r * (size_t)src_ld + c0 + c]);
    }
}

__global__ __launch_bounds__(256) void gather_emb(
    const int* __restrict__ target, const float* __restrict__ emb,
    ushort* __restrict__ dst)
{
    const int row = blockIdx.x;          // b*T + t
    const int b = row >> 6;
    const int t = row & 63;
    const int tok = (t == 0) ? 1 : target[b * T_ + t - 1];
    const float* e = emb + (size_t)tok * E_;
    ushort* d = dst + (size_t)row * E_;
    for (int c = threadIdx.x; c < E_; c += 256) d[c] = f2bf(e[c]);
}

__global__ __launch_bounds__(256) void pack_bhq(
    const float* __restrict__ ba, const float* __restrict__ bhh,
    float* __restrict__ dst)
{
    const int j = blockIdx.x * 256 + threadIdx.x;
    if (j < H_) dst[j] = ba[j];
    else if (j < QGH_) dst[j] = bhh[j - H_];
}

// ---------------------------------------------------------------------------
// K1: qgh = h_prev @ [Wa_q; W_hh]^T + [ba;b_hh]   (M=64, N=4096, K=1024)
// 256 blocks x 512 thr. Block owns 16-col slice. Wave (mt = w&3, kh = w>>2):
// m-tile mt, K-half kh; fragments loaded straight from global (L2-hot).
// ---------------------------------------------------------------------------
__global__ __launch_bounds__(512) void qgh_step(
    const ushort* __restrict__ hprev, int ldh,
    const ushort* __restrict__ Whq,
    const float* __restrict__ bhq,
    float* __restrict__ qgh)
{
    const int n0 = blockIdx.x * 16;
    const int tid = threadIdx.x;
    const int wv = tid >> 6;
    const int lane = tid & 63;
    const int mt = wv & 3;
    const int kh = wv >> 2;
    const int frow = lane & 15;
    const int fk = (lane >> 4) * 8;

    const ushort* Arow = hprev + (size_t)(mt * 16 + frow) * ldh + kh * 512 + fk;
    const ushort* Brow = Whq + (size_t)(n0 + frow) * H_ + kh * 512 + fk;

    f32x4 acc = (f32x4){0.f, 0.f, 0.f, 0.f};
#pragma unroll
    for (int c = 0; c < 16; ++c) {
        bf16x8 a = *reinterpret_cast<const bf16x8*>(Arow + c * 32);
        bf16x8 b = *reinterpret_cast<const bf16x8*>(Brow + c * 32);
        acc = __builtin_amdgcn_mfma_f32_16x16x32_bf16(a, b, acc, 0, 0, 0);
    }

    __shared__ f32x4 red[8][64];
    red[wv][lane] = acc;
    __syncthreads();

    if (wv < 4) {
        f32x4 s = red[wv][lane] + red[wv + 4][lane];
        const int col = n0 + frow;
        const float bv = bhq[col];
        const int row0 = wv * 16 + (lane >> 4) * 4;
#pragma unroll
        for (int r = 0; r < 4; ++r)
            qgh[(size_t)(row0 + r) * QGH_ + col] = s[r] + bv;
    }
}

// ---------------------------------------------------------------------------
// K2: scores[b,s] = sum_h v[h]*tanh(q[b,h] + encp[b,s,h])
// 256 blocks (b = bk>>2, s-slice 32) x 512 thr (8 waves x 4 rows).
// ---------------------------------------------------------------------------
__global__ __launch_bounds__(512) void scores_step(
    const ushort* __restrict__ encp,
    const float* __restrict__ qgh,
    const float* __restrict__ vvec,
    float* __restrict__ scores)
{
    const int b  = blockIdx.x >> 2;
    const int s0 = (blockIdx.x & 3) * 32;
    const int tid = threadIdx.x;

    __shared__ float qs[H_];
    __shared__ float vs[H_];
    qs[tid]       = qgh[(size_t)b * QGH_ + tid];
    qs[tid + 512] = qgh[(size_t)b * QGH_ + tid + 512];
    vs[tid]       = vvec[tid];
    vs[tid + 512] = vvec[tid + 512];
    __syncthreads();

    const int wv = tid >> 6;
    const int lane = tid & 63;
    const int h0 = lane * 16;

#pragma unroll
    for (int i = 0; i < 4; ++i) {
        const int s = s0 + wv * 4 + i;
        const ushort* ep = encp + ((size_t)b * S_ + s) * H_ + h0;
        float p = 0.f;
#pragma unroll
        for (int v8 = 0; v8 < 2; ++v8) {
            u16x8 ev = *reinterpret_cast<const u16x8*>(ep + v8 * 8);
#pragma unroll
            for (int j = 0; j < 8; ++j) {
                const int h = h0 + v8 * 8 + j;
                p += vs[h] * tanhf(qs[h] + bf2f(ev[j]));
            }
        }
#pragma unroll
        for (int off = 32; off; off >>= 1) p += __shfl_xor(p, off);
        if (lane == 0) scores[b * S_ + s] = p;
    }
}

// ---------------------------------------------------------------------------
// K3: softmax over s (per b) + ctx[b, e-slice] = sum_s alpha[s]*enc[b,s,e]
// 256 blocks (b = bk>>2, e-slice 512) x 512 thr.
// ---------------------------------------------------------------------------
__global__ __launch_bounds__(512) void ctx_step(
    const float* __restrict__ scores,
    const ushort* __restrict__ enc,
    ushort* __restrict__ ctx)
{
    const int b  = blockIdx.x >> 2;
    const int e0 = (blockIdx.x & 3) * 512;
    const int tid = threadIdx.x;

    __shared__ float al[S_];
    if (tid < 64) {
        float a0 = scores[b * S_ + tid];
        float a1 = scores[b * S_ + tid + 64];
        float m = fmaxf(a0, a1);
#pragma unroll
        for (int off = 32; off; off >>= 1) m = fmaxf(m, __shfl_xor(m, off));
        float e0v = expf(a0 - m), e1v = expf(a1 - m);
        float ssum = e0v + e1v;
#pragma unroll
        for (int off = 32; off; off >>= 1) ssum += __shfl_xor(ssum, off);
        const float inv = 1.f / ssum;
        al[tid] = e0v * inv;
        al[tid + 64] = e1v * inv;
    }
    __syncthreads();

    const int e = e0 + tid;
    const ushort* eb = enc + (size_t)b * S_ * ENC_ + e;
    float acc = 0.f;
#pragma unroll 8
    for (int s = 0; s < S_; ++s)
        acc = fmaf(al[s], bf2f(eb[(size_t)s * ENC_]), acc);
    ctx[(size_t)b * ENC_ + e] = f2bf(acc);
}

// ---------------------------------------------------------------------------
// K4: gictx = ctx @ W_ih[:,E:]^T   (M=64, N=3072, K=2048)
// 192 blocks x 512 thr; wave (mt = w&3, kh = w>>2) as K1.
// ---------------------------------------------------------------------------
__global__ __launch_bounds__(512) void gi_step(
    const ushort* __restrict__ ctx,
    const ushort* __restrict__ Wie,
    float* __restrict__ gictx)
{
    const int n0 = blockIdx.x * 16;
    const int tid = threadIdx.x;
    const int wv = tid >> 6;
    const int lane = tid & 63;
    const int mt = wv & 3;
    const int kh = wv >> 2;
    const int frow = lane & 15;
    const int fk = (lane >> 4) * 8;

    const ushort* Arow = ctx + (size_t)(mt * 16 + frow) * ENC_ + kh * 1024 + fk;
    const ushort* Brow = Wie + (size_t)(n0 + frow) * ENC_ + kh * 1024 + fk;

    f32x4 acc = (f32x4){0.f, 0.f, 0.f, 0.f};
#pragma unroll 8
    for (int c = 0; c < 32; ++c) {
        bf16x8 a = *reinterpret_cast<const bf16x8*>(Arow + c * 32);
        bf16x8 b = *reinterpret_cast<const bf16x8*>(Brow + c * 32);
        acc = __builtin_amdgcn_mfma_f32_16x16x32_bf16(a, b, acc, 0, 0, 0);
    }

    __shared__ f32x4 red[8][64];
    red[wv][lane] = acc;
    __syncthreads();

    if (wv < 4) {
        f32x4 s = red[wv][lane] + red[wv + 4][lane];
        const int col = n0 + frow;
        const int row0 = wv * 16 + (lane >> 4) * 4;
#pragma unroll
        for (int r = 0; r < 4; ++r)
            gictx[(size_t)(row0 + r) * G3_ + col] = s[r];
    }
}

// ---------------------------------------------------------------------------
// K5: GRU pointwise
// ---------------------------------------------------------------------------
__global__ __launch_bounds__(256) void gru_step_k(
    const float* __restrict__ gictx,
    const float* __restrict__ giemb,
    const float* __restrict__ qgh,
    const float* __restrict__ hprev, int ldh,
    float* __restrict__ hall_f,
    ushort* __restrict__ hall_b,
    int t)
{
    const int idx = blockIdx.x * 256 + threadIdx.x;   // 0..B*H-1
    const int b = idx >> 10;
    const int j = idx & (H_ - 1);

    const size_t gr = (size_t)(b * T_ + t) * G3_;
    const float ir  = gictx[(size_t)b * G3_ + j]           + giemb[gr + j];
    const float iz  = gictx[(size_t)b * G3_ + H_ + j]      + giemb[gr + H_ + j];
    const float in_ = gictx[(size_t)b * G3_ + 2 * H_ + j]  + giemb[gr + 2 * H_ + j];

    const float* ghp = qgh + (size_t)b * QGH_ + H_;
    const float hr = ghp[j];
    const float hz = ghp[H_ + j];
    const float hn = ghp[2 * H_ + j];

    const float r = sigmoidf_(ir + hr);
    const float z = sigmoidf_(iz + hz);
    const float n = tanhf(in_ + r * hn);
    const float hp = hprev[(size_t)b * ldh + j];
    const float hnew = (1.f - z) * n + z * hp;

    const size_t ho = (size_t)b * (T_ * H_) + (size_t)t * H_ + j;
    hall_f[ho] = hnew;
    hall_b[ho] = f2bf(hnew);
}

// ---------------------------------------------------------------------------
static inline int pgrid(size_t total) {
    size_t nb = (total + 255) / 256;
    if (nb > 4096) nb = 4096;
    return (int)nb;
}

extern "C" void kernel_launch(void* const* d_in, const int* in_sizes, int n_in,
                              void* d_out, int out_size, void* d_ws, size_t ws_size,
                              hipStream_t stream) {
    const float* enc    = (const float*)d_in[0];
    const float* enc_h  = (const float*)d_in[1];
    const int*   target = (const int*)  d_in[2];
    const float* emb    = (const float*)d_in[3];
    const float* Wa     = (const float*)d_in[4];
    const float* ba     = (const float*)d_in[5];
    const float* vvec   = (const float*)d_in[6];
    const float* W_ih   = (const float*)d_in[7];
    const float* b_ih   = (const float*)d_in[8];
    const float* W_hh   = (const float*)d_in[9];
    const float* b_hh   = (const float*)d_in[10];
    const float* Wo     = (const float*)d_in[11];
    const float* bo     = (const float*)d_in[12];
    float* out = (float*)d_out;

    char* p = (char*)d_ws;
    auto alloc_u16 = [&](size_t n) { ushort* r = (ushort*)p; p += n * 2; return r; };
    auto alloc_f32 = [&](size_t n) { float* r = (float*)p; p += n * 4; return r; };

    ushort* enc_bf  = alloc_u16((size_t)B_ * S_ * ENC_);
    ushort* encp_bf = alloc_u16((size_t)B_ * S_ * H_);
    ushort* Wo_bf   = alloc_u16((size_t)V_ * H_);
    ushort* Wae_bf  = alloc_u16((size_t)H_ * ENC_);
    ushort* Whq_bf  = alloc_u16((size_t)QGH_ * H_);
    ushort* Wie_bf  = alloc_u16((size_t)G3_ * ENC_);
    ushort* Wiee_bf = alloc_u16((size_t)G3_ * E_);
    ushort* ench_bf = alloc_u16((size_t)B_ * H_);
    ushort* Xemb_bf = alloc_u16((size_t)B_ * T_ * E_);
    ushort* hall_bf = alloc_u16((size_t)B_ * T_ * H_);
    ushort* ctx_bf  = alloc_u16((size_t)B_ * ENC_);
    float* hall_f   = alloc_f32((size_t)B_ * T_ * H_);
    float* giemb    = alloc_f32((size_t)B_ * T_ * G3_);
    float* qgh      = alloc_f32((size_t)B_ * QGH_);
    float* gictx    = alloc_f32((size_t)B_ * G3_);
    float* bhq      = alloc_f32((size_t)QGH_);
    float* scores   = alloc_f32((size_t)B_ * S_);

    const int LDW = H_ + ENC_;   // 3072

    // ---- packs ----
    pack_bf16<<<pgrid((size_t)B_*S_*ENC_), 256, 0, stream>>>(enc, ENC_, 0, ENC_, enc_bf, (size_t)B_*S_*ENC_);
    pack_bf16<<<pgrid((size_t)V_*H_), 256, 0, stream>>>(Wo, H_, 0, H_, Wo_bf, (size_t)V_*H_);
    pack_bf16<<<pgrid((size_t)H_*ENC_), 256, 0, stream>>>(Wa, LDW, H_, ENC_, Wae_bf, (size_t)H_*ENC_);
    pack_bf16<<<pgrid((size_t)H_*H_), 256, 0, stream>>>(Wa, LDW, 0, H_, Whq_bf, (size_t)H_*H_);
    pack_bf16<<<pgrid((size_t)G3_*H_), 256, 0, stream>>>(W_hh, H_, 0, H_, Whq_bf + (size_t)H_*H_, (size_t)G3_*H_);
    pack_bf16<<<pgrid((size_t)G3_*ENC_), 256, 0, stream>>>(W_ih, XDIM_, E_, ENC_, Wie_bf, (size_t)G3_*ENC_);
    pack_bf16<<<pgrid((size_t)G3_*E_), 256, 0, stream>>>(W_ih, XDIM_, 0, E_, Wiee_bf, (size_t)G3_*E_);
    pack_bf16<<<pgrid((size_t)B_*H_), 256, 0, stream>>>(enc_h, H_, 0, H_, ench_bf, (size_t)B_*H_);
    gather_emb<<<B_*T_, 256, 0, stream>>>(target, emb, Xemb_bf);
    pack_bhq<<<QGH_/256, 256, 0, stream>>>(ba, b_hh, bhq);

    // ---- big parallel GEMMs (m97 structure) ----
    // enc_proj: (B*S,H) = enc_bf @ Wae^T  (bf16 out, no bias — ba lives in q)
    gemm128_bf16<<<dim3(H_/128, (B_*S_)/128), 256, 0, stream>>>(
        enc_bf, ENC_, Wae_bf, ENC_, nullptr, nullptr, encp_bf, H_, ENC_);
    // gi_emb: (B*T,3H) = Xemb @ W_ih[:, :E]^T + b_ih (fp32 out)
    gemm128_bf16<<<dim3(G3_/128, (B_*T_)/128), 256, 0, stream>>>(
        Xemb_bf, E_, Wiee_bf, E_, b_ih, giemb, nullptr, G3_, E_);

    // ---- recurrence: 5 wide dispatches per step ----
    for (int t = 0; t < T_; ++t) {
        const ushort* hprev_bf = (t == 0) ? ench_bf : (hall_bf + (size_t)(t-1) * H_);
        const float*  hprev_f  = (t == 0) ? enc_h   : (hall_f  + (size_t)(t-1) * H_);
        const int ldh = (t == 0) ? H_ : (T_ * H_);

        qgh_step<<<256, 512, 0, stream>>>(hprev_bf, ldh, Whq_bf, bhq, qgh);
        scores_step<<<256, 512, 0, stream>>>(encp_bf, qgh, vvec, scores);
        ctx_step<<<256, 512, 0, stream>>>(scores, enc_bf, ctx_bf);
        gi_step<<<192, 512, 0, stream>>>(ctx_bf, Wie_bf, gictx);
        gru_step_k<<<256, 256, 0, stream>>>(gictx, giemb, qgh, hprev_f, ldh,
                                            hall_f, hall_bf, t);
    }

    // ---- output projection: (B*T,V) = hall_bf @ Wo^T + bo ----
    gemm128_bf16<<<dim3(V_/128, (B_*T_)/128), 256, 0, stream>>>(
        hall_bf, H_, Wo_bf, H_, bo, out, nullptr, V_, H_);
}